// Round 12
// baseline (335.929 us; speedup 1.0000x reference)
//
#include <hip/hip_runtime.h>
#include <hip/hip_bf16.h>

typedef float  f32x4  __attribute__((ext_vector_type(4)));
typedef float  f32x16 __attribute__((ext_vector_type(16)));
typedef short  s16x8  __attribute__((ext_vector_type(8)));
typedef unsigned int u32;

__device__ __forceinline__ short f2bf(float f) {
    union { float f; u32 u; } c; c.f = f;
    return (short)((c.u + 0x8000u) >> 16);
}
__device__ __forceinline__ float bf2f(u32 v) {
    union { u32 u; float f; } c; c.u = v << 16; return c.f;
}
__device__ __forceinline__ u32 cvtpk(float lo, float hi) {
    u32 r;
    asm("v_cvt_pk_bf16_f32 %0, %1, %2" : "=v"(r) : "v"(lo), "v"(hi));
    return r;
}
__device__ __forceinline__ s16x8 cvt8(float4 f0, float4 f1) {
    union { s16x8 v; u32 w[4]; } u;
    u.w[0] = cvtpk(f0.x, f0.y); u.w[1] = cvtpk(f0.z, f0.w);
    u.w[2] = cvtpk(f1.x, f1.y); u.w[3] = cvtpk(f1.z, f1.w);
    return u.v;
}
__device__ __forceinline__ s16x8 cvt8v(f32x4 a, f32x4 b) {
    union { s16x8 v; u32 w[4]; } u;
    u.w[0] = cvtpk(a[0], a[1]); u.w[1] = cvtpk(a[2], a[3]);
    u.w[2] = cvtpk(b[0], b[1]); u.w[3] = cvtpk(b[2], b[3]);
    return u.v;
}
__device__ __forceinline__ void gload16(const void* g, void* l) {
    __builtin_amdgcn_global_load_lds((const __attribute__((address_space(1))) u32*)g,
                                     (__attribute__((address_space(3))) u32*)l, 16, 0, 0);
}

#define MFMA32(a, b, c) __builtin_amdgcn_mfma_f32_32x32x16_bf16((a), (b), (c), 0, 0, 0)
#define MFMA16(a, b, c) __builtin_amdgcn_mfma_f32_16x16x32_bf16((a), (b), (c), 0, 0, 0)
#define ZS 1040   // z-tile LDS row stride in bytes (65*16: rotates bank-group start per row)

// ---------- pack for 16x16x32 fragments (W_out only) ----------
__global__ void pack_w(const float* __restrict__ W, short* __restrict__ out,
                       int Kreal, int N, int nbTot, int total) {
    int tid = blockIdx.x * 256 + threadIdx.x;
    if (tid >= total) return;
    int j  = tid & 7;
    int l  = (tid >> 3) & 63;
    int blk = tid >> 9;
    int nb = blk % nbTot, ks = blk / nbTot;
    int k = ks * 32 + (l >> 4) * 8 + j;
    int n = nb * 16 + (l & 15);
    out[tid] = (k < Kreal) ? f2bf(W[(long)k * N + n]) : (short)0;
}

// ---------- pack for 32x32x16 fragments: row=l&31 (feat), k=(l>>5)*8+j ----------
__global__ void pack_w32(const float* __restrict__ W, short* __restrict__ out,
                         int Kreal, int N, int nbTot, int total) {
    int tid = blockIdx.x * 256 + threadIdx.x;
    if (tid >= total) return;
    int j  = tid & 7;
    int l  = (tid >> 3) & 63;
    int blk = tid >> 9;                 // ks*nbTot + nb
    int nb = blk % nbTot, ks = blk / nbTot;
    int k = ks * 16 + (l >> 5) * 8 + j;
    int n = nb * 32 + (l & 31);
    out[tid] = (k < Kreal) ? f2bf(W[(long)k * N + n]) : (short)0;
}

// acc layout (32x32 swapped): col = batch = lane&31; feat(reg) = (reg&3)+8*(reg>>2)+4*hi
__device__ __forceinline__ void initC(f32x16& a, const float* p, int base, int hi) {
#pragma unroll
    for (int q = 0; q < 4; ++q) {
        float4 v = *(const float4*)(p + base + q * 8 + hi * 4);
        a[q * 4 + 0] = v.x; a[q * 4 + 1] = v.y; a[q * 4 + 2] = v.z; a[q * 4 + 3] = v.w;
    }
}
__device__ __forceinline__ void addC(f32x16& a, const float* p, int base, int hi) {
#pragma unroll
    for (int q = 0; q < 4; ++q) {
        float4 v = *(const float4*)(p + base + q * 8 + hi * 4);
        a[q * 4 + 0] += v.x; a[q * 4 + 1] += v.y; a[q * 4 + 2] += v.z; a[q * 4 + 3] += v.w;
    }
}

// ---------- layernorm over 256 feats; batch = lane&31, wave owns 64 feats ----------
__device__ __forceinline__ void ln32(f32x16& a0, f32x16& a1,
                                     const float* __restrict__ g, const float* __restrict__ bl,
                                     float2* red, int lane, int b, int hi, int w, int fb) {
    float s = 0.f, q = 0.f;
#pragma unroll
    for (int i = 0; i < 16; ++i) {
        s += a0[i] + a1[i];
        q += a0[i] * a0[i] + a1[i] * a1[i];
    }
    s += __shfl_xor(s, 32); q += __shfl_xor(q, 32);
    if (lane < 32) red[b * 4 + w] = make_float2(s, q);
    __syncthreads();
    float2 p0 = red[b * 4 + 0], p1 = red[b * 4 + 1];
    float2 p2 = red[b * 4 + 2], p3 = red[b * 4 + 3];
    float S = (p0.x + p1.x) + (p2.x + p3.x);
    float Q = (p0.y + p1.y) + (p2.y + p3.y);
    float mean = S * (1.f / 256.f);
    float var  = fmaxf(Q * (1.f / 256.f) - mean * mean, 0.f);
    float rstd = rsqrtf(var + 1e-5f);
#pragma unroll
    for (int nb = 0; nb < 2; ++nb) {
        f32x16& a = nb ? a1 : a0;
#pragma unroll
        for (int qd = 0; qd < 4; ++qd) {
            float4 gv = *(const float4*)(g  + fb + nb * 32 + qd * 8 + hi * 4);
            float4 bv = *(const float4*)(bl + fb + nb * 32 + qd * 8 + hi * 4);
            a[qd * 4 + 0] = (a[qd * 4 + 0] - mean) * rstd * gv.x + bv.x;
            a[qd * 4 + 1] = (a[qd * 4 + 1] - mean) * rstd * gv.y + bv.y;
            a[qd * 4 + 2] = (a[qd * 4 + 2] - mean) * rstd * gv.z + bv.z;
            a[qd * 4 + 3] = (a[qd * 4 + 3] - mean) * rstd * gv.w + bv.w;
        }
    }
}

// ---------------- main fused kernel: 4 waves, 32 batch rows, 32x32 MFMA ----------------
__global__ __launch_bounds__(256, 4) void deq_main(
    const float* __restrict__ x, const float* __restrict__ z,
    const float* __restrict__ b_inp, const float* __restrict__ g_lni, const float* __restrict__ b_lni,
    const float* __restrict__ b1, const float* __restrict__ g_ln1, const float* __restrict__ b_ln1,
    const float* __restrict__ b2, const float* __restrict__ g_ln2, const float* __restrict__ b_ln2,
    const float* __restrict__ g_ln3, const float* __restrict__ b_ln3,
    const float* __restrict__ b_out,
    const s16x8* __restrict__ Wp1, const s16x8* __restrict__ Wp2,
    const s16x8* __restrict__ WpI, const s16x8* __restrict__ WpO,
    float* __restrict__ out_dx, float* __restrict__ out_z)
{
    // [0, 32*ZS): z-tile f32 (rows of 1KB at stride ZS, linear), overlaid by T_sh
    // ([32][256] bf16, 512B rows, XOR-swizzled) after LN1's barrier. Then LN stats.
    __shared__ __align__(16) char smem[32 * ZS + 4096];
    short*  T_sh = (short*)smem;
    float2* red  = (float2*)(smem + 32 * ZS);

    const int tid  = threadIdx.x;
    const int w    = tid >> 6;
    const int lane = tid & 63;
    const int b    = lane & 31;       // batch row
    const int hi   = lane >> 5;       // k-half / feat-offset selector
    const int fb   = w * 64;          // wave's feature base
    const int fbn  = w * 2;           // wave's 32-feat block base
    const int r = lane & 15, kg = lane >> 4;   // out-GEMM 16x16 indices
    const long r0 = (long)blockIdx.x * 32;
    const int swzb = (b & 7) << 4;

    // ---- DMA: stage z tile (linear source); wave w stages rows [w*8, w*8+8) ----
#pragma unroll
    for (int i = 0; i < 8; ++i) {
        int row = w * 8 + i;
        const char* gp = (const char*)(z + (r0 + row) * 256) + lane * 16;
        gload16(gp, smem + row * ZS);
    }

    // ---- pre-barrier: x loads + x-GEMM (no LDS deps) fill the DMA-drain shadow ----
    f32x16 xacc0, xacc1;
    initC(xacc0, b_inp, fb, hi);
    initC(xacc1, b_inp, fb + 32, hi);
    {
        const float* xr = x + (r0 + b) * 48 + hi * 8;
        float4 xv0 = ((const float4*)(xr))[0],      xv1 = ((const float4*)(xr + 4))[0];
        float4 xv2 = ((const float4*)(xr + 16))[0], xv3 = ((const float4*)(xr + 20))[0];
        float4 xv4 = ((const float4*)(xr + 32))[0], xv5 = ((const float4*)(xr + 36))[0];
        s16x8 a0 = cvt8(xv0, xv1);
        s16x8 a1 = cvt8(xv2, xv3);
        s16x8 a2 = cvt8(xv4, xv5);
        xacc0 = MFMA32(WpI[(0 * 8 + fbn + 0) * 64 + lane], a0, xacc0);
        xacc1 = MFMA32(WpI[(0 * 8 + fbn + 1) * 64 + lane], a0, xacc1);
        xacc0 = MFMA32(WpI[(1 * 8 + fbn + 0) * 64 + lane], a1, xacc0);
        xacc1 = MFMA32(WpI[(1 * 8 + fbn + 1) * 64 + lane], a1, xacc1);
        xacc0 = MFMA32(WpI[(2 * 8 + fbn + 0) * 64 + lane], a2, xacc0);
        xacc1 = MFMA32(WpI[(2 * 8 + fbn + 1) * 64 + lane], a2, xacc1);
    }

    // W1 prefetch (depth 2) issued pre-barrier: lands in regs during the DMA drain
    s16x8 c0 = Wp1[(fbn + 0) * 64 + lane];
    s16x8 c1 = Wp1[(fbn + 1) * 64 + lane];
    s16x8 d0 = Wp1[(8 + fbn + 0) * 64 + lane];
    s16x8 d1 = Wp1[(8 + fbn + 1) * 64 + lane];

    f32x16 acc0, acc1;
    initC(acc0, b1, fb, hi);
    initC(acc1, b1, fb + 32, hi);

    __syncthreads();   // drains DMA + x + weight prefetch in one vmcnt(0)

    // ================= GEMM1: C = W1^T · z^T (+b1), A-frags from LDS z ==============
    {
        const char* zrow = (const char*)smem + b * ZS;
#pragma unroll
        for (int ks = 0; ks < 16; ++ks) {
            s16x8 e0, e1;
            if (ks < 14) {
                e0 = Wp1[((ks + 2) * 8 + fbn + 0) * 64 + lane];
                e1 = Wp1[((ks + 2) * 8 + fbn + 1) * 64 + lane];
            }
            const int c = ks * 64 + hi * 32;
            f32x4 p0 = *(const f32x4*)(zrow + c);
            f32x4 p1 = *(const f32x4*)(zrow + c + 16);
            s16x8 a = cvt8v(p0, p1);
            acc0 = MFMA32(c0, a, acc0);
            acc1 = MFMA32(c1, a, acc1);
            c0 = d0; c1 = d1; d0 = e0; d1 = e1;
        }
    }

    // relu + LN1 -> z1
#pragma unroll
    for (int i = 0; i < 16; ++i) { acc0[i] = fmaxf(acc0[i], 0.f); acc1[i] = fmaxf(acc1[i], 0.f); }
    ln32(acc0, acc1, g_ln1, b_ln1, red + 0 * 128, lane, b, hi, w, fb);

    // pack z1 (regs, residual) + stage to T_sh ([b][256] bf16, XOR-swizzled)
    u32 z1p[2][8];
#pragma unroll
    for (int nb = 0; nb < 2; ++nb) {
        f32x16& a = nb ? acc1 : acc0;
#pragma unroll
        for (int qd = 0; qd < 4; ++qd) {
            z1p[nb][qd * 2 + 0] = cvtpk(a[qd * 4 + 0], a[qd * 4 + 1]);
            z1p[nb][qd * 2 + 1] = cvtpk(a[qd * 4 + 2], a[qd * 4 + 3]);
        }
    }
#pragma unroll
    for (int nb = 0; nb < 2; ++nb)
#pragma unroll
        for (int qd = 0; qd < 4; ++qd) {
            int fbyte = (fb + nb * 32 + qd * 8 + hi * 4) * 2;
            *(uint2*)((char*)T_sh + b * 512 + (fbyte ^ swzb)) =
                make_uint2(z1p[nb][qd * 2], z1p[nb][qd * 2 + 1]);
        }

    // W2 prefetch (depth 2) before LN_inp's barrier
    c0 = Wp2[(fbn + 0) * 64 + lane];
    c1 = Wp2[(fbn + 1) * 64 + lane];
    d0 = Wp2[(8 + fbn + 0) * 64 + lane];
    d1 = Wp2[(8 + fbn + 1) * 64 + lane];

    // LN_inp on xacc (barrier also orders all waves' z1 staging before GEMM2 reads)
    ln32(xacc0, xacc1, g_lni, b_lni, red + 1 * 128, lane, b, hi, w, fb);

    // + b2 (C-init for GEMM2)
    addC(xacc0, b2, fb, hi);
    addC(xacc1, b2, fb + 32, hi);

    // ================= GEMM2: C += W2^T · z1^T (z1-frags from T_sh) =================
    {
        const char* zr = (const char*)T_sh + b * 512;
#pragma unroll
        for (int ks = 0; ks < 16; ++ks) {
            s16x8 e0, e1;
            if (ks < 14) {
                e0 = Wp2[((ks + 2) * 8 + fbn + 0) * 64 + lane];
                e1 = Wp2[((ks + 2) * 8 + fbn + 1) * 64 + lane];
            }
            s16x8 az = *(const s16x8*)(zr + ((ks * 32 + hi * 16) ^ swzb));
            xacc0 = MFMA32(c0, az, xacc0);
            xacc1 = MFMA32(c1, az, xacc1);
            c0 = d0; c1 = d1; d0 = e0; d1 = e1;
        }
    }
    ln32(xacc0, xacc1, g_ln2, b_ln2, red + 2 * 128, lane, b, hi, w, fb);   // inner

    // ---- z_out = LN3(relu(z1 + inner)); z1 from registers ----
#pragma unroll
    for (int nb = 0; nb < 2; ++nb) {
        f32x16& a = nb ? xacc1 : xacc0;
#pragma unroll
        for (int qd = 0; qd < 4; ++qd) {
            a[qd * 4 + 0] = fmaxf(a[qd * 4 + 0] + bf2f(z1p[nb][qd * 2] & 0xffffu), 0.f);
            a[qd * 4 + 1] = fmaxf(a[qd * 4 + 1] + bf2f(z1p[nb][qd * 2] >> 16), 0.f);
            a[qd * 4 + 2] = fmaxf(a[qd * 4 + 2] + bf2f(z1p[nb][qd * 2 + 1] & 0xffffu), 0.f);
            a[qd * 4 + 3] = fmaxf(a[qd * 4 + 3] + bf2f(z1p[nb][qd * 2 + 1] >> 16), 0.f);
        }
    }
    ln32(xacc0, xacc1, g_ln3, b_ln3, red + 3 * 128, lane, b, hi, w, fb);   // z_out

    // stage z_out to T_sh (overwrites z1 — safe past LN2/LN3 barriers)
#pragma unroll
    for (int nb = 0; nb < 2; ++nb) {
        f32x16& a = nb ? xacc1 : xacc0;
#pragma unroll
        for (int qd = 0; qd < 4; ++qd) {
            u32 w0 = cvtpk(a[qd * 4 + 0], a[qd * 4 + 1]);
            u32 w1 = cvtpk(a[qd * 4 + 2], a[qd * 4 + 3]);
            int fbyte = (fb + nb * 32 + qd * 8 + hi * 4) * 2;
            *(uint2*)((char*)T_sh + b * 512 + (fbyte ^ swzb)) = make_uint2(w0, w1);
        }
    }
    __syncthreads();

    // ======= out-GEMM (16x16 path): dx = z_out @ W_out (+b_out); wave -> (mi, nbo) =======
    {
        const int mi = w & 1, nbo = w >> 1;
        float bb = b_out[nbo * 16 + r];
        f32x4 ao = (f32x4){bb, bb, bb, bb};
#pragma unroll
        for (int ks = 0; ks < 8; ++ks) {
            int R = mi * 16 + r;
            int off = R * 512 + ((ks * 64 + kg * 16) ^ ((R & 7) << 4));
            s16x8 a0 = *(const s16x8*)((const char*)T_sh + off);
            s16x8 bw = WpO[(ks * 2 + nbo) * 64 + lane];
            ao = MFMA16(a0, bw, ao);
        }
#pragma unroll
        for (int j = 0; j < 4; ++j)
            out_dx[(r0 + mi * 16 + kg * 4 + j) * 32 + nbo * 16 + r] = ao[j];
    }

    // ---- coalesced out_z: T_sh bf16 -> f32; wave w copies rows [w*8, w*8+8) ----
    {
        float* zo = out_z + r0 * 256;
#pragma unroll
        for (int it = 0; it < 4; ++it) {
            int row = w * 8 + it * 2 + (lane >> 5);
            int addr = row * 512 + (((lane & 31) * 16) ^ ((row & 7) << 4));
            int4 wd = *(const int4*)((const char*)T_sh + addr);
            float4 o0, o1;
            o0.x = bf2f((u32)wd.x & 0xffffu); o0.y = bf2f((u32)wd.x >> 16);
            o0.z = bf2f((u32)wd.y & 0xffffu); o0.w = bf2f((u32)wd.y >> 16);
            o1.x = bf2f((u32)wd.z & 0xffffu); o1.y = bf2f((u32)wd.z >> 16);
            o1.z = bf2f((u32)wd.w & 0xffffu); o1.w = bf2f((u32)wd.w >> 16);
            int e = row * 256 + (lane & 31) * 8;
            *(float4*)(zo + e) = o0;
            *(float4*)(zo + e + 4) = o1;
        }
    }
}

extern "C" void kernel_launch(void* const* d_in, const int* in_sizes, int n_in,
                              void* d_out, int out_size, void* d_ws, size_t ws_size,
                              hipStream_t stream) {
    const float* x      = (const float*)d_in[0];
    const float* z      = (const float*)d_in[1];
    const float* W_inp  = (const float*)d_in[2];
    const float* b_inp  = (const float*)d_in[3];
    const float* g_lni  = (const float*)d_in[4];
    const float* b_lni  = (const float*)d_in[5];
    const float* W1     = (const float*)d_in[6];
    const float* b1     = (const float*)d_in[7];
    const float* g_ln1  = (const float*)d_in[8];
    const float* b_ln1  = (const float*)d_in[9];
    const float* W2     = (const float*)d_in[10];
    const float* b2     = (const float*)d_in[11];
    const float* g_ln2  = (const float*)d_in[12];
    const float* b_ln2  = (const float*)d_in[13];
    const float* g_ln3  = (const float*)d_in[14];
    const float* b_ln3  = (const float*)d_in[15];
    const float* W_out  = (const float*)d_in[16];
    const float* b_out  = (const float*)d_in[17];

    short* Wp1 = (short*)d_ws;            // 16ks*8nb*512 = 65536 bf16 (32x32 frags)
    short* Wp2 = Wp1 + 65536;             // 65536
    short* WpI = Wp2 + 65536;             // 3ks*8nb*512  = 12288
    short* WpO = WpI + 12288;             // 8*2*512      = 8192 (16x16 frags)

    pack_w32<<<256, 256, 0, stream>>>(W1,    Wp1, 256, 256, 8, 65536);
    pack_w32<<<256, 256, 0, stream>>>(W2,    Wp2, 256, 256, 8, 65536);
    pack_w32<<< 48, 256, 0, stream>>>(W_inp, WpI,  48, 256, 8, 12288);
    pack_w  <<< 32, 256, 0, stream>>>(W_out, WpO, 256,  32, 2,  8192);

    const long B = 262144;
    float* out_dx = (float*)d_out;
    float* out_z  = out_dx + B * 32;
    deq_main<<<B / 32, 256, 0, stream>>>(x, z, b_inp, g_lni, b_lni,
                                         b1, g_ln1, b_ln1, b2, g_ln2, b_ln2,
                                         g_ln3, b_ln3, b_out,
                                         (const s16x8*)Wp1, (const s16x8*)Wp2,
                                         (const s16x8*)WpI, (const s16x8*)WpO,
                                         out_dx, out_z);
}

// Round 13
// 246.285 us; speedup vs baseline: 1.3640x; 1.3640x over previous
//
#include <hip/hip_runtime.h>
#include <hip/hip_bf16.h>

typedef float  f32x4  __attribute__((ext_vector_type(4)));
typedef float  f32x16 __attribute__((ext_vector_type(16)));
typedef short  s16x8  __attribute__((ext_vector_type(8)));
typedef unsigned int u32;

__device__ __forceinline__ short f2bf(float f) {
    union { float f; u32 u; } c; c.f = f;
    return (short)((c.u + 0x8000u) >> 16);
}
__device__ __forceinline__ float bf2f(u32 v) {
    union { u32 u; float f; } c; c.u = v << 16; return c.f;
}
__device__ __forceinline__ u32 cvtpk(float lo, float hi) {
    u32 r;
    asm("v_cvt_pk_bf16_f32 %0, %1, %2" : "=v"(r) : "v"(lo), "v"(hi));
    return r;
}
__device__ __forceinline__ s16x8 cvt8(float4 f0, float4 f1) {
    union { s16x8 v; u32 w[4]; } u;
    u.w[0] = cvtpk(f0.x, f0.y); u.w[1] = cvtpk(f0.z, f0.w);
    u.w[2] = cvtpk(f1.x, f1.y); u.w[3] = cvtpk(f1.z, f1.w);
    return u.v;
}

#define MFMA32(a, b, c) __builtin_amdgcn_mfma_f32_32x32x16_bf16((a), (b), (c), 0, 0, 0)
#define MFMA16(a, b, c) __builtin_amdgcn_mfma_f32_16x16x32_bf16((a), (b), (c), 0, 0, 0)

// ---------- pack for 16x16x32 fragments (W_out only) ----------
__global__ void pack_w(const float* __restrict__ W, short* __restrict__ out,
                       int Kreal, int N, int nbTot, int total) {
    int tid = blockIdx.x * 256 + threadIdx.x;
    if (tid >= total) return;
    int j  = tid & 7;
    int l  = (tid >> 3) & 63;
    int blk = tid >> 9;
    int nb = blk % nbTot, ks = blk / nbTot;
    int k = ks * 32 + (l >> 4) * 8 + j;
    int n = nb * 16 + (l & 15);
    out[tid] = (k < Kreal) ? f2bf(W[(long)k * N + n]) : (short)0;
}

// ---------- pack for 32x32x16 fragments: row=l&31 (feat), k=(l>>5)*8+j ----------
__global__ void pack_w32(const float* __restrict__ W, short* __restrict__ out,
                         int Kreal, int N, int nbTot, int total) {
    int tid = blockIdx.x * 256 + threadIdx.x;
    if (tid >= total) return;
    int j  = tid & 7;
    int l  = (tid >> 3) & 63;
    int blk = tid >> 9;                 // ks*nbTot + nb
    int nb = blk % nbTot, ks = blk / nbTot;
    int k = ks * 16 + (l >> 5) * 8 + j;
    int n = nb * 32 + (l & 31);
    out[tid] = (k < Kreal) ? f2bf(W[(long)k * N + n]) : (short)0;
}

// acc layout (32x32 swapped): col = batch = lane&31; feat(reg) = (reg&3)+8*(reg>>2)+4*hi
__device__ __forceinline__ void initC(f32x16& a, const float* p, int base, int hi) {
#pragma unroll
    for (int q = 0; q < 4; ++q) {
        float4 v = *(const float4*)(p + base + q * 8 + hi * 4);
        a[q * 4 + 0] = v.x; a[q * 4 + 1] = v.y; a[q * 4 + 2] = v.z; a[q * 4 + 3] = v.w;
    }
}
__device__ __forceinline__ void addC(f32x16& a, const float* p, int base, int hi) {
#pragma unroll
    for (int q = 0; q < 4; ++q) {
        float4 v = *(const float4*)(p + base + q * 8 + hi * 4);
        a[q * 4 + 0] += v.x; a[q * 4 + 1] += v.y; a[q * 4 + 2] += v.z; a[q * 4 + 3] += v.w;
    }
}

// ---------- layernorm over 256 feats, two batch rows (b and b+32) per lane ----------
__device__ __forceinline__ void ln64(f32x16& a00, f32x16& a01, f32x16& a10, f32x16& a11,
                                     const float* __restrict__ g, const float* __restrict__ bl,
                                     float2* red, int lane, int b, int hi, int w, int fb) {
    float sA = 0.f, qA = 0.f, sB = 0.f, qB = 0.f;
#pragma unroll
    for (int i = 0; i < 16; ++i) {
        sA += a00[i] + a01[i]; qA += a00[i] * a00[i] + a01[i] * a01[i];
        sB += a10[i] + a11[i]; qB += a10[i] * a10[i] + a11[i] * a11[i];
    }
    sA += __shfl_xor(sA, 32); qA += __shfl_xor(qA, 32);
    sB += __shfl_xor(sB, 32); qB += __shfl_xor(qB, 32);
    if (lane < 32) {
        red[b * 4 + w] = make_float2(sA, qA);
        red[(b + 32) * 4 + w] = make_float2(sB, qB);
    }
    __syncthreads();
    float2 a0 = red[b * 4 + 0], a1 = red[b * 4 + 1], a2 = red[b * 4 + 2], a3 = red[b * 4 + 3];
    float2 c0 = red[(b + 32) * 4 + 0], c1 = red[(b + 32) * 4 + 1];
    float2 c2 = red[(b + 32) * 4 + 2], c3 = red[(b + 32) * 4 + 3];
    float SA = (a0.x + a1.x) + (a2.x + a3.x), QA = (a0.y + a1.y) + (a2.y + a3.y);
    float SB = (c0.x + c1.x) + (c2.x + c3.x), QB = (c0.y + c1.y) + (c2.y + c3.y);
    float mA = SA * (1.f / 256.f);
    float rA = rsqrtf(fmaxf(QA * (1.f / 256.f) - mA * mA, 0.f) + 1e-5f);
    float mB = SB * (1.f / 256.f);
    float rB = rsqrtf(fmaxf(QB * (1.f / 256.f) - mB * mB, 0.f) + 1e-5f);
#pragma unroll
    for (int nb = 0; nb < 2; ++nb) {
        f32x16& xA = nb ? a01 : a00;
        f32x16& xB = nb ? a11 : a10;
#pragma unroll
        for (int qd = 0; qd < 4; ++qd) {
            float4 gv = *(const float4*)(g  + fb + nb * 32 + qd * 8 + hi * 4);
            float4 bv = *(const float4*)(bl + fb + nb * 32 + qd * 8 + hi * 4);
            xA[qd * 4 + 0] = (xA[qd * 4 + 0] - mA) * rA * gv.x + bv.x;
            xA[qd * 4 + 1] = (xA[qd * 4 + 1] - mA) * rA * gv.y + bv.y;
            xA[qd * 4 + 2] = (xA[qd * 4 + 2] - mA) * rA * gv.z + bv.z;
            xA[qd * 4 + 3] = (xA[qd * 4 + 3] - mA) * rA * gv.w + bv.w;
            xB[qd * 4 + 0] = (xB[qd * 4 + 0] - mB) * rB * gv.x + bv.x;
            xB[qd * 4 + 1] = (xB[qd * 4 + 1] - mB) * rB * gv.y + bv.y;
            xB[qd * 4 + 2] = (xB[qd * 4 + 2] - mB) * rB * gv.z + bv.z;
            xB[qd * 4 + 3] = (xB[qd * 4 + 3] - mB) * rB * gv.w + bv.w;
        }
    }
}

// ---------------- main fused kernel: 4 waves, 64 batch rows, 32x32 MFMA ----------------
__global__ __launch_bounds__(256, 4) void deq_main(
    const float* __restrict__ x, const float* __restrict__ z,
    const float* __restrict__ b_inp, const float* __restrict__ g_lni, const float* __restrict__ b_lni,
    const float* __restrict__ b1, const float* __restrict__ g_ln1, const float* __restrict__ b_ln1,
    const float* __restrict__ b2, const float* __restrict__ g_ln2, const float* __restrict__ b_ln2,
    const float* __restrict__ g_ln3, const float* __restrict__ b_ln3,
    const float* __restrict__ b_out,
    const s16x8* __restrict__ Wp1, const s16x8* __restrict__ Wp2,
    const s16x8* __restrict__ WpI, const s16x8* __restrict__ WpO,
    float* __restrict__ out_dx, float* __restrict__ out_z)
{
    // Z_sh[64][256] bf16, 512B rows, swz(row) = (row&31)<<4. Holds z, then z1, then z_out.
    __shared__ __align__(16) short Z_sh[64 * 256];    // 32 KB
    __shared__ float2 red0[64 * 4], red1[64 * 4];     // 2 x 2 KB, alternating LN stat buffers

    const int tid  = threadIdx.x;
    const int w    = tid >> 6;
    const int lane = tid & 63;
    const int b    = lane & 31;       // batch row (half A); half B = b+32
    const int hi   = lane >> 5;
    const int fb   = w * 64;          // wave's feature base
    const int fbn  = w * 2;           // wave's 32-feat block base
    const int r = lane & 15, kg = lane >> 4;   // out-GEMM 16x16 indices
    const long r0 = (long)blockIdx.x * 64;
    const int swzb = b << 4;

    // ---- stage z (64 x 256 f32 -> bf16), coalesced loads, swizzled b128 LDS writes ----
#pragma unroll
    for (int i = 0; i < 8; ++i) {
        int c = i * 256 + tid;
        int row = c >> 5, ch = c & 31;
        const float4* gp = (const float4*)(z + (r0 + row) * 256 + ch * 8);
        float4 f0 = gp[0], f1 = gp[1];
        union { int4 v; u32 u[4]; } pk;
        pk.u[0] = cvtpk(f0.x, f0.y); pk.u[1] = cvtpk(f0.z, f0.w);
        pk.u[2] = cvtpk(f1.x, f1.y); pk.u[3] = cvtpk(f1.z, f1.w);
        *(int4*)((char*)Z_sh + row * 512 + ((ch * 16) ^ ((row & 31) << 4))) = pk.v;
    }
    __syncthreads();

    f32x16 acc00, acc01, acc10, acc11;   // [batch-half][feat-block]

    // ================= GEMM1: C = W1^T · z^T (+b1), bf16 A-frags from LDS ==============
    initC(acc00, b1, fb, hi);
    initC(acc01, b1, fb + 32, hi);
    acc10 = acc00; acc11 = acc01;
    {
        const char* zr0 = (const char*)Z_sh + b * 512;
        const char* zr1 = zr0 + 32 * 512;            // (b+32)&31 == b -> same swizzle
        s16x8 c0 = Wp1[(fbn + 0) * 64 + lane];
        s16x8 c1 = Wp1[(fbn + 1) * 64 + lane];
#pragma unroll
        for (int ks = 0; ks < 16; ++ks) {
            s16x8 n0, n1;
            if (ks < 15) {
                n0 = Wp1[((ks + 1) * 8 + fbn + 0) * 64 + lane];
                n1 = Wp1[((ks + 1) * 8 + fbn + 1) * 64 + lane];
            }
            int off = (ks * 32 + hi * 16) ^ swzb;
            s16x8 aA = *(const s16x8*)(zr0 + off);
            s16x8 aB = *(const s16x8*)(zr1 + off);
            acc00 = MFMA32(c0, aA, acc00);
            acc10 = MFMA32(c0, aB, acc10);
            acc01 = MFMA32(c1, aA, acc01);
            acc11 = MFMA32(c1, aB, acc11);
            c0 = n0; c1 = n1;
        }
    }

    // relu + LN1 -> z1
#pragma unroll
    for (int i = 0; i < 16; ++i) {
        acc00[i] = fmaxf(acc00[i], 0.f); acc01[i] = fmaxf(acc01[i], 0.f);
        acc10[i] = fmaxf(acc10[i], 0.f); acc11[i] = fmaxf(acc11[i], 0.f);
    }
    ln64(acc00, acc01, acc10, acc11, g_ln1, b_ln1, red0, lane, b, hi, w, fb);

    // stage z1 into Z_sh (overwrites z; all GEMM1 reads done at LN1's barrier)
#pragma unroll
    for (int hf = 0; hf < 2; ++hf) {
        int row = b + hf * 32;
#pragma unroll
        for (int nb = 0; nb < 2; ++nb) {
            f32x16& a = hf ? (nb ? acc11 : acc10) : (nb ? acc01 : acc00);
#pragma unroll
            for (int qd = 0; qd < 4; ++qd) {
                u32 w0 = cvtpk(a[qd * 4 + 0], a[qd * 4 + 1]);
                u32 w1 = cvtpk(a[qd * 4 + 2], a[qd * 4 + 3]);
                int fbyte = (fb + nb * 32 + qd * 8 + hi * 4) * 2;
                *(uint2*)((char*)Z_sh + row * 512 + (fbyte ^ swzb)) = make_uint2(w0, w1);
            }
        }
    }

    // ================= x-GEMM: C = W_inp^T · x^T (+b_inp), x loaded at use =============
    initC(acc00, b_inp, fb, hi);
    initC(acc01, b_inp, fb + 32, hi);
    acc10 = acc00; acc11 = acc01;
    {
        const float* xr0 = x + (r0 + b) * 48 + hi * 8;
        const float* xr1 = x + (r0 + 32 + b) * 48 + hi * 8;
#pragma unroll
        for (int ks = 0; ks < 3; ++ks) {
            float4 fA0 = ((const float4*)(xr0 + ks * 16))[0];
            float4 fA1 = ((const float4*)(xr0 + ks * 16 + 4))[0];
            float4 fB0 = ((const float4*)(xr1 + ks * 16))[0];
            float4 fB1 = ((const float4*)(xr1 + ks * 16 + 4))[0];
            s16x8 aA = cvt8(fA0, fA1);
            s16x8 aB = cvt8(fB0, fB1);
            s16x8 w0 = WpI[(ks * 8 + fbn + 0) * 64 + lane];
            s16x8 w1 = WpI[(ks * 8 + fbn + 1) * 64 + lane];
            acc00 = MFMA32(w0, aA, acc00);
            acc10 = MFMA32(w0, aB, acc10);
            acc01 = MFMA32(w1, aA, acc01);
            acc11 = MFMA32(w1, aB, acc11);
        }
    }
    // LN_inp (its barrier orders all waves' z1 staging before GEMM2 reads)
    ln64(acc00, acc01, acc10, acc11, g_lni, b_lni, red1, lane, b, hi, w, fb);

    // + b2 (C-init for GEMM2)
    addC(acc00, b2, fb, hi);      addC(acc01, b2, fb + 32, hi);
    addC(acc10, b2, fb, hi);      addC(acc11, b2, fb + 32, hi);

    // ================= GEMM2: C += W2^T · z1^T (z1-frags from Z_sh) =================
    {
        const char* zr0 = (const char*)Z_sh + b * 512;
        const char* zr1 = zr0 + 32 * 512;
        s16x8 c0 = Wp2[(fbn + 0) * 64 + lane];
        s16x8 c1 = Wp2[(fbn + 1) * 64 + lane];
#pragma unroll
        for (int ks = 0; ks < 16; ++ks) {
            s16x8 n0, n1;
            if (ks < 15) {
                n0 = Wp2[((ks + 1) * 8 + fbn + 0) * 64 + lane];
                n1 = Wp2[((ks + 1) * 8 + fbn + 1) * 64 + lane];
            }
            int off = (ks * 32 + hi * 16) ^ swzb;
            s16x8 aA = *(const s16x8*)(zr0 + off);
            s16x8 aB = *(const s16x8*)(zr1 + off);
            acc00 = MFMA32(c0, aA, acc00);
            acc10 = MFMA32(c0, aB, acc10);
            acc01 = MFMA32(c1, aA, acc01);
            acc11 = MFMA32(c1, aB, acc11);
            c0 = n0; c1 = n1;
        }
    }
    ln64(acc00, acc01, acc10, acc11, g_ln2, b_ln2, red0, lane, b, hi, w, fb);   // inner

    // ---- z_out = LN3(relu(z1 + inner)); z1 re-read from Z_sh (lane's own chunks) ----
#pragma unroll
    for (int hf = 0; hf < 2; ++hf) {
        int row = b + hf * 32;
#pragma unroll
        for (int nb = 0; nb < 2; ++nb) {
            f32x16& a = hf ? (nb ? acc11 : acc10) : (nb ? acc01 : acc00);
#pragma unroll
            for (int qd = 0; qd < 4; ++qd) {
                int fbyte = (fb + nb * 32 + qd * 8 + hi * 4) * 2;
                uint2 v = *(const uint2*)((const char*)Z_sh + row * 512 + (fbyte ^ swzb));
                a[qd * 4 + 0] = fmaxf(a[qd * 4 + 0] + bf2f(v.x & 0xffffu), 0.f);
                a[qd * 4 + 1] = fmaxf(a[qd * 4 + 1] + bf2f(v.x >> 16), 0.f);
                a[qd * 4 + 2] = fmaxf(a[qd * 4 + 2] + bf2f(v.y & 0xffffu), 0.f);
                a[qd * 4 + 3] = fmaxf(a[qd * 4 + 3] + bf2f(v.y >> 16), 0.f);
            }
        }
    }
    ln64(acc00, acc01, acc10, acc11, g_ln3, b_ln3, red1, lane, b, hi, w, fb);   // z_out

    // stage z_out into Z_sh (overwrites z1; all z1 reads done at LN3's barrier)
#pragma unroll
    for (int hf = 0; hf < 2; ++hf) {
        int row = b + hf * 32;
#pragma unroll
        for (int nb = 0; nb < 2; ++nb) {
            f32x16& a = hf ? (nb ? acc11 : acc10) : (nb ? acc01 : acc00);
#pragma unroll
            for (int qd = 0; qd < 4; ++qd) {
                u32 w0 = cvtpk(a[qd * 4 + 0], a[qd * 4 + 1]);
                u32 w1 = cvtpk(a[qd * 4 + 2], a[qd * 4 + 3]);
                int fbyte = (fb + nb * 32 + qd * 8 + hi * 4) * 2;
                *(uint2*)((char*)Z_sh + row * 512 + (fbyte ^ swzb)) = make_uint2(w0, w1);
            }
        }
    }
    __syncthreads();

    // ======= out-GEMM (16x16): dx = z_out @ W_out (+b_out); wave w -> rows [w*16,w*16+16) ==
    {
        f32x4 ao[2];
#pragma unroll
        for (int nbo = 0; nbo < 2; ++nbo) {
            float bb = b_out[nbo * 16 + r];
            ao[nbo] = (f32x4){bb, bb, bb, bb};
        }
        const int R = w * 16 + r;
        const int swzR = (R & 31) << 4;
#pragma unroll
        for (int ks = 0; ks < 8; ++ks) {
            int off = R * 512 + ((ks * 64 + kg * 16) ^ swzR);
            s16x8 a0 = *(const s16x8*)((const char*)Z_sh + off);
#pragma unroll
            for (int nbo = 0; nbo < 2; ++nbo)
                ao[nbo] = MFMA16(a0, WpO[(ks * 2 + nbo) * 64 + lane], ao[nbo]);
        }
#pragma unroll
        for (int nbo = 0; nbo < 2; ++nbo)
#pragma unroll
            for (int j = 0; j < 4; ++j)
                out_dx[(r0 + w * 16 + kg * 4 + j) * 32 + nbo * 16 + r] = ao[nbo][j];
    }

    // ---- coalesced out_z: Z_sh bf16 -> f32; wave w copies rows [w*16, w*16+16) ----
    {
        float* zo = out_z + r0 * 256;
#pragma unroll
        for (int it = 0; it < 8; ++it) {
            int row = w * 16 + it * 2 + (lane >> 5);
            int addr = row * 512 + (((lane & 31) * 16) ^ ((row & 31) << 4));
            int4 wd = *(const int4*)((const char*)Z_sh + addr);
            float4 o0, o1;
            o0.x = bf2f((u32)wd.x & 0xffffu); o0.y = bf2f((u32)wd.x >> 16);
            o0.z = bf2f((u32)wd.y & 0xffffu); o0.w = bf2f((u32)wd.y >> 16);
            o1.x = bf2f((u32)wd.z & 0xffffu); o1.y = bf2f((u32)wd.z >> 16);
            o1.z = bf2f((u32)wd.w & 0xffffu); o1.w = bf2f((u32)wd.w >> 16);
            int e = row * 256 + (lane & 31) * 8;
            *(float4*)(zo + e) = o0;
            *(float4*)(zo + e + 4) = o1;
        }
    }
}

extern "C" void kernel_launch(void* const* d_in, const int* in_sizes, int n_in,
                              void* d_out, int out_size, void* d_ws, size_t ws_size,
                              hipStream_t stream) {
    const float* x      = (const float*)d_in[0];
    const float* z      = (const float*)d_in[1];
    const float* W_inp  = (const float*)d_in[2];
    const float* b_inp  = (const float*)d_in[3];
    const float* g_lni  = (const float*)d_in[4];
    const float* b_lni  = (const float*)d_in[5];
    const float* W1     = (const float*)d_in[6];
    const float* b1     = (const float*)d_in[7];
    const float* g_ln1  = (const float*)d_in[8];
    const float* b_ln1  = (const float*)d_in[9];
    const float* W2     = (const float*)d_in[10];
    const float* b2     = (const float*)d_in[11];
    const float* g_ln2  = (const float*)d_in[12];
    const float* b_ln2  = (const float*)d_in[13];
    const float* g_ln3  = (const float*)d_in[14];
    const float* b_ln3  = (const float*)d_in[15];
    const float* W_out  = (const float*)d_in[16];
    const float* b_out  = (const float*)d_in[17];

    short* Wp1 = (short*)d_ws;            // 16ks*8nb*512 = 65536 bf16 (32x32 frags)
    short* Wp2 = Wp1 + 65536;             // 65536
    short* WpI = Wp2 + 65536;             // 3ks*8nb*512  = 12288
    short* WpO = WpI + 12288;             // 8*2*512      = 8192 (16x16 frags)

    pack_w32<<<256, 256, 0, stream>>>(W1,    Wp1, 256, 256, 8, 65536);
    pack_w32<<<256, 256, 0, stream>>>(W2,    Wp2, 256, 256, 8, 65536);
    pack_w32<<< 48, 256, 0, stream>>>(W_inp, WpI,  48, 256, 8, 12288);
    pack_w  <<< 32, 256, 0, stream>>>(W_out, WpO, 256,  32, 2,  8192);

    const long B = 262144;
    float* out_dx = (float*)d_out;
    float* out_z  = out_dx + B * 32;
    deq_main<<<B / 64, 256, 0, stream>>>(x, z, b_inp, g_lni, b_lni,
                                         b1, g_ln1, b_ln1, b2, g_ln2, b_ln2,
                                         g_ln3, b_ln3, b_out,
                                         (const s16x8*)Wp1, (const s16x8*)Wp2,
                                         (const s16x8*)WpI, (const s16x8*)WpO,
                                         out_dx, out_z);
}